// Round 4
// baseline (80.906 us; speedup 1.0000x reference)
//
#include <hip/hip_runtime.h>

// PEPS 6x6 amplitude, D=3, B samples. Bidirectional (fwd: rows x=0..2,
// bwd: rows x=3..5) + half-column factorization: per interior row x,
// precompute V-independent half-row tensors G (y=0..2, l-pinned) and
// B (y=3..5, r-pinned); applying row x to the boundary vector is then
// just F = V*G and newV = F*B (2 barrier phases instead of 6).
// A perm layout: u*27 + d*9 + l*3 + r. Fwd contracts u (SS=27), outputs
// d (SO=9); bwd contracts d, outputs u.

constexpr int SITE_STRIDE = 81 * 32; // floats per site in T

__global__ __launch_bounds__(512)
void peps_amp_kernel(const int* __restrict__ xs, const float* __restrict__ T,
                     float* __restrict__ out) {
    __shared__ float A[36 * 81];
    __shared__ float Vsh[2][729];       // boundary vectors per half
    __shared__ float Gsh[2][2][2187];   // [half][col] G[(o012)*81 + g*27 + u012]
    __shared__ float Bsh[2][2][2187];   // [half][col] B[(o345)*81 + g*27 + u345]
    __shared__ float Fsh[2][2187];      // F[(o012)*81 + g*27 + u345]
    __shared__ float T01sh[2][2][243];  // [u01*27 + o01*3 + b2]
    __shared__ float T45sh[2][2][243];  // [u45*27 + o45*3 + b4]
    __shared__ float red[8];
    __shared__ int sidx[36];

    const int b = blockIdx.x;
    const int t = threadIdx.x;
    const int half = t >> 8;   // 0 = fwd (x=0,1,2), 1 = bwd (x=5,4,3)
    const int lt = t & 255;

    if (t < 36) {
        const int i = t / 6, j = t % 6;
        const int base = b * 36;
        const int p  = xs[base + t];
        const int pu = (i > 0) ? xs[base + t - 6] : 0;
        const int pd = (i < 5) ? xs[base + t + 6] : 0;
        const int pl = (j > 0) ? xs[base + t - 1] : 0;
        const int pr = (j < 5) ? xs[base + t + 1] : 0;
        sidx[t] = (((p * 2 + pu) * 2 + pd) * 2 + pl) * 2 + pr;
    }
    __syncthreads();
    for (int idx = t; idx < 36 * 81; idx += 512) {
        const int site = idx / 81;
        const int perm = idx - site * 81;
        A[idx] = T[site * SITE_STRIDE + perm * 32 + sidx[site]];
    }
    __syncthreads();

    const int SS = half ? 9 : 27;   // contracted vertical leg stride
    const int SO = half ? 27 : 9;   // output vertical leg stride

    // ---- P1: boundary-row vector (x=0 fwd / x=5 bwd) + pair temps T01,T45
    {
        const float* Ab = &A[(half ? 30 : 0) * 81];
        for (int idx = lt; idx < 1701; idx += 256) {
            if (idx < 729) {
                const int k = idx;
                const int c0 = k / 243, c1 = (k / 81) % 3, c2 = (k / 27) % 3;
                const int c3 = (k / 9) % 3, c4 = (k / 3) % 3, c5 = k % 3;
                float v0 = Ab[c0 * SO + 0];
                float v1 = Ab[c0 * SO + 1];
                float v2 = Ab[c0 * SO + 2];
                const float* P1p = Ab + 81 + c1 * SO;
                float n0 = v0 * P1p[0] + v1 * P1p[3] + v2 * P1p[6];
                float n1 = v0 * P1p[1] + v1 * P1p[4] + v2 * P1p[7];
                float n2 = v0 * P1p[2] + v1 * P1p[5] + v2 * P1p[8];
                const float* P2p = Ab + 162 + c2 * SO;
                v0 = n0 * P2p[0] + n1 * P2p[3] + n2 * P2p[6];
                v1 = n0 * P2p[1] + n1 * P2p[4] + n2 * P2p[7];
                v2 = n0 * P2p[2] + n1 * P2p[5] + n2 * P2p[8];
                const float* P3p = Ab + 243 + c3 * SO;
                n0 = v0 * P3p[0] + v1 * P3p[3] + v2 * P3p[6];
                n1 = v0 * P3p[1] + v1 * P3p[4] + v2 * P3p[7];
                n2 = v0 * P3p[2] + v1 * P3p[5] + v2 * P3p[8];
                const float* P4p = Ab + 324 + c4 * SO;
                v0 = n0 * P4p[0] + n1 * P4p[3] + n2 * P4p[6];
                v1 = n0 * P4p[1] + n1 * P4p[4] + n2 * P4p[7];
                v2 = n0 * P4p[2] + n1 * P4p[5] + n2 * P4p[8];
                const float* P5p = Ab + 405 + c5 * SO;
                Vsh[half][k] = v0 * P5p[0] + v1 * P5p[3] + v2 * P5p[6];
            } else if (idx < 729 + 486) {
                int e = idx - 729;
                const int c = e / 243; e -= c * 243;
                const int u01 = e / 27, o01 = (e / 3) % 9, b2 = e % 3;
                const int u0 = u01 / 3, u1 = u01 % 3, o0 = o01 / 3, o1 = o01 % 3;
                const float* Ar = &A[(half ? (4 - c) : (1 + c)) * 486];
                float acc = 0.f;
                #pragma unroll
                for (int b1 = 0; b1 < 3; ++b1)
                    acc += Ar[u0 * SS + o0 * SO + b1] *
                           Ar[81 + u1 * SS + o1 * SO + b1 * 3 + b2];
                T01sh[half][c][e] = acc;
            } else {
                int e = idx - 729 - 486;
                const int c = e / 243; e -= c * 243;
                const int u45 = e / 27, o45 = (e / 3) % 9, b4 = e % 3;
                const int u4 = u45 / 3, u5 = u45 % 3, o4 = o45 / 3, o5 = o45 % 3;
                const float* Ar = &A[(half ? (4 - c) : (1 + c)) * 486];
                float acc = 0.f;
                #pragma unroll
                for (int b5 = 0; b5 < 3; ++b5)
                    acc += Ar[324 + u4 * SS + o4 * SO + b4 * 3 + b5] *
                           Ar[405 + u5 * SS + o5 * SO + b5 * 3];
                T45sh[half][c][e] = acc;
            }
        }
    }
    __syncthreads();

    // ---- P2: half-row tensors G (y=0..2) and B (y=3..5) for both columns
    for (int idx = lt; idx < 8748; idx += 256) {
        const int c = idx / 4374;
        int rem = idx - c * 4374;
        const int isB = rem / 2187;
        const int e = rem - isB * 2187;
        const int oc = e / 81, g = (e / 27) % 3, uc = e % 27;
        const float* Ar = &A[(half ? (4 - c) : (1 + c)) * 486];
        float acc = 0.f;
        if (!isB) {
            const int o01 = oc / 3, o2 = oc % 3, u01 = uc / 3, u2 = uc % 3;
            const float* t01 = &T01sh[half][c][u01 * 27 + o01 * 3];
            const float* a2 = &Ar[162 + u2 * SS + o2 * SO];
            #pragma unroll
            for (int b2 = 0; b2 < 3; ++b2)
                acc += t01[b2] * a2[b2 * 3 + g];
            Gsh[half][c][e] = acc;
        } else {
            const int o3 = oc / 9, o45 = oc % 9, u3 = uc / 9, u45 = uc % 9;
            const float* a3 = &Ar[243 + u3 * SS + o3 * SO + g * 3];
            const float* t45 = &T45sh[half][c][u45 * 27 + o45 * 3];
            #pragma unroll
            for (int b4 = 0; b4 < 3; ++b4)
                acc += a3[b4] * t45[b4];
            Bsh[half][c][e] = acc;
        }
    }
    __syncthreads();

    // ---- two interior rows per half, 2 phases each
    for (int c = 0; c < 2; ++c) {
        const float* G = Gsh[half][c];
        const float* Bt = Bsh[half][c];
        float* F = Fsh[half];
        float* V = Vsh[half];

        // F[(oc012), g, (uc345)] = sum_{uc012} V[uc012*27+uc345] * G[oc012,g,uc012]
        if (lt < 243) {
            const int oc = lt / 9;
            const int gk = lt - oc * 9;
            const int g = gk / 3, k = gk - g * 3;   // uc345 = k*9 + m
            float acc[9] = {0, 0, 0, 0, 0, 0, 0, 0, 0};
            const float* Grow = &G[oc * 81 + g * 27];
            #pragma unroll
            for (int u = 0; u < 27; ++u) {
                const float gv = Grow[u];
                const float* vp = &V[u * 27 + k * 9];
                #pragma unroll
                for (int m = 0; m < 9; ++m) acc[m] += gv * vp[m];
            }
            float* Fp = &F[oc * 81 + g * 27 + k * 9];
            #pragma unroll
            for (int m = 0; m < 9; ++m) Fp[m] = acc[m];
        }
        __syncthreads();

        // newV[oc012*27 + oc345] = sum_{g,uc345} F[oc012,g,uc345] * B[oc345,g,uc345]
        if (lt < 243) {
            const int oc = lt / 9;          // oc012
            const int q = lt - oc * 9;      // o3*3 + o4 ; outputs o5 = 0..2
            float a0 = 0.f, a1 = 0.f, a2v = 0.f;
            #pragma unroll
            for (int g = 0; g < 3; ++g) {
                const float* Fp = &F[oc * 81 + g * 27];
                const float* B0 = &Bt[(q * 3 + 0) * 81 + g * 27];
                const float* B1 = &Bt[(q * 3 + 1) * 81 + g * 27];
                const float* B2 = &Bt[(q * 3 + 2) * 81 + g * 27];
                #pragma unroll
                for (int u = 0; u < 27; ++u) {
                    const float fv = Fp[u];
                    a0 += fv * B0[u];
                    a1 += fv * B1[u];
                    a2v += fv * B2[u];
                }
            }
            V[oc * 27 + q * 3 + 0] = a0;
            V[oc * 27 + q * 3 + 1] = a1;
            V[oc * 27 + q * 3 + 2] = a2v;
        }
        __syncthreads();
    }

    // ---- amplitude = Vf . Vb
    float partial = 0.f;
    for (int i = t; i < 729; i += 512) partial += Vsh[0][i] * Vsh[1][i];
    #pragma unroll
    for (int off = 32; off > 0; off >>= 1) partial += __shfl_down(partial, off);
    if ((t & 63) == 0) red[t >> 6] = partial;
    __syncthreads();
    if (t == 0) {
        float s = 0.f;
        #pragma unroll
        for (int w = 0; w < 8; ++w) s += red[w];
        out[b] = s;
    }
}

extern "C" void kernel_launch(void* const* d_in, const int* in_sizes, int n_in,
                              void* d_out, int out_size, void* d_ws, size_t ws_size,
                              hipStream_t stream) {
    const int* xs = (const int*)d_in[0];
    const float* T = (const float*)d_in[1];
    float* out = (float*)d_out;
    const int B = in_sizes[0] / 36;
    peps_amp_kernel<<<B, 512, 0, stream>>>(xs, T, out);
}

// Round 5
// 71.661 us; speedup vs baseline: 1.1290x; 1.1290x over previous
//
#include <hip/hip_runtime.h>

// PEPS 6x6 amplitude, D=3, B samples. Bidirectional boundary contraction
// (fwd waves: rows x=0..2 top-down; bwd waves: rows x=5..3 bottom-up),
// amplitude = Vf . Vb. Round-5 refinements over the round-3 structure:
//  - sidx computed inline in the gather (no setup barriers)
//  - boundary row via pair-products P01,P23,P45 built directly from T
//    during the gather phase (12 FMA/config instead of a 6-matvec chain)
//  - interior column sweep fuses y-steps (1,2) and (3,4): phases per
//    column = 4 (y0, f12, f34, y5), each <=162 FMA/thread.
// A perm layout: u*27 + d*9 + l*3 + r. Fwd contracts u (SS=27), outputs
// d (SO=9); bwd contracts d (SS=9), outputs u (SO=27).

constexpr int SITE_STRIDE = 81 * 32; // floats per site in T

__device__ __forceinline__ int calc_sidx(const int* __restrict__ xs, int base, int s) {
    const int i = s / 6, j = s - (s / 6) * 6;
    const int p  = xs[base + s];
    const int pu = (i > 0) ? xs[base + s - 6] : 0;
    const int pd = (i < 5) ? xs[base + s + 6] : 0;
    const int pl = (j > 0) ? xs[base + s - 1] : 0;
    const int pr = (j < 5) ? xs[base + s + 1] : 0;
    return (((p * 2 + pu) * 2 + pd) * 2 + pl) * 2 + pr;
}

// Fused application of two y-sites. Input layout [D(3^y... as composite),
// l, s, m, ur(U)]; output [(D,o1,o2,r2), ur(U)].
template <int U>
__device__ __forceinline__ void fused2(int lt, const float* __restrict__ Win,
                                       float* __restrict__ Wout,
                                       const float* __restrict__ A1,
                                       const float* __restrict__ A2,
                                       int SS, int SO) {
    if (lt >= 243) return;
    const int D  = lt / (3 * U);
    const int rem = lt - D * 3 * U;
    const int o1 = rem / U;
    const int ur = rem - o1 * U;
    const float* Wb = Win + D * 27 * U + ur;
    float win[3][3][3]; // [l][s][m]
    #pragma unroll
    for (int l = 0; l < 3; ++l)
        #pragma unroll
        for (int s = 0; s < 3; ++s)
            #pragma unroll
            for (int m = 0; m < 3; ++m)
                win[l][s][m] = Wb[((l * 9 + s * 3 + m) * U)];
    float tt[3][3]; // [r1][m]
    #pragma unroll
    for (int r1 = 0; r1 < 3; ++r1)
        #pragma unroll
        for (int m = 0; m < 3; ++m) {
            float acc = 0.f;
            #pragma unroll
            for (int s = 0; s < 3; ++s)
                #pragma unroll
                for (int l = 0; l < 3; ++l)
                    acc += win[l][s][m] * A1[s * SS + o1 * SO + l * 3 + r1];
            tt[r1][m] = acc;
        }
    float* Wo = Wout + (D * 3 + o1) * 9 * U + ur;
    #pragma unroll
    for (int o2 = 0; o2 < 3; ++o2)
        #pragma unroll
        for (int r2 = 0; r2 < 3; ++r2) {
            float acc = 0.f;
            #pragma unroll
            for (int m = 0; m < 3; ++m)
                #pragma unroll
                for (int r1 = 0; r1 < 3; ++r1)
                    acc += tt[r1][m] * A2[m * SS + o2 * SO + r1 * 3 + r2];
            Wo[(o2 * 3 + r2) * U] = acc;
        }
}

__global__ __launch_bounds__(512)
void peps_amp_kernel(const int* __restrict__ xs, const float* __restrict__ T,
                     float* __restrict__ out) {
    __shared__ float A[36 * 81];
    __shared__ float Vsh[2][729];
    __shared__ float Wsh[2][2][2187];
    __shared__ float Pm[2][3][81]; // pair-products of boundary-row sites
    __shared__ float red[8];

    const int b = blockIdx.x;
    const int t = threadIdx.x;
    const int half = t >> 8;   // 0 = fwd (x=0,1,2), 1 = bwd (x=5,4,3)
    const int lt = t & 255;
    const int base = b * 36;

    // ---- gather A slices + boundary pair-products, sidx inline (1 phase)
    for (int idx = t; idx < 2916 + 486; idx += 512) {
        if (idx < 2916) {
            const int site = idx / 81;
            const int perm = idx - site * 81;
            A[idx] = T[site * SITE_STRIDE + perm * 32 + calc_sidx(xs, base, site)];
        } else {
            const int e = idx - 2916;
            const int ph = e / 243;
            const int rem = e - ph * 243;
            const int p = rem / 81;
            const int q = rem - p * 81;
            const int cc2 = q / 9, lr = q - cc2 * 9;
            const int ca = cc2 / 3, cb = cc2 - ca * 3;
            const int l = lr / 3, r = lr - l * 3;
            const int SOh = ph ? 27 : 9;
            const int sa = (ph ? 30 : 0) + 2 * p;
            const int sb = sa + 1;
            const int sxa = calc_sidx(xs, base, sa);
            const int sxb = calc_sidx(xs, base, sb);
            const float* Ta = T + sa * SITE_STRIDE + sxa;
            const float* Tb = T + sb * SITE_STRIDE + sxb;
            float acc = 0.f;
            #pragma unroll
            for (int m = 0; m < 3; ++m)
                acc += Ta[(ca * SOh + l * 3 + m) * 32] *
                       Tb[(cb * SOh + m * 3 + r) * 32];
            Pm[ph][p][q] = acc;
        }
    }
    __syncthreads();

    const int SS = half ? 9 : 27;
    const int SO = half ? 27 : 9;
    float* V  = Vsh[half];
    float* Wa = Wsh[half][0];
    float* Wb = Wsh[half][1];

    // ---- boundary row via pair-products (1 phase)
    for (int k = lt; k < 729; k += 256) {
        const int c01 = k / 81;
        const int c23 = (k / 9) % 9;
        const int c45 = k % 9;
        const float* p0 = &Pm[half][0][c01 * 9]; // row l=0
        const float* p1 = &Pm[half][1][c23 * 9];
        const float* p2 = &Pm[half][2][c45 * 9]; // col r=0
        float w0 = p0[0] * p1[0] + p0[1] * p1[3] + p0[2] * p1[6];
        float w1 = p0[0] * p1[1] + p0[1] * p1[4] + p0[2] * p1[7];
        float w2 = p0[0] * p1[2] + p0[1] * p1[5] + p0[2] * p1[8];
        V[k] = w0 * p2[0] + w1 * p2[3] + w2 * p2[6];
    }
    __syncthreads();

    // ---- two interior rows per half, 4 phases each
    for (int cc = 0; cc < 2; ++cc) {
        const int xc = half ? (4 - cc) : (1 + cc);
        const float* Arow = &A[xc * 486];

        // y = 0 (l pinned 0): V[729] -> Wa[2187]
        if (lt < 243) {
            const float v0 = V[lt], v1 = V[243 + lt], v2 = V[486 + lt];
            const float* A0 = Arow;
            #pragma unroll
            for (int o = 0; o < 3; ++o)
                #pragma unroll
                for (int r = 0; r < 3; ++r) {
                    Wa[(o * 3 + r) * 243 + lt] =
                        v0 * A0[o * SO + r] +
                        v1 * A0[SS + o * SO + r] +
                        v2 * A0[2 * SS + o * SO + r];
                }
        }
        __syncthreads();

        fused2<27>(lt, Wa, Wb, Arow + 81, Arow + 162, SS, SO);
        __syncthreads();
        fused2<3>(lt, Wb, Wa, Arow + 243, Arow + 324, SS, SO);
        __syncthreads();

        // y = 5 (r pinned 0): Wa[2187] -> V[729]
        if (lt < 243) {
            const float* Ay = Arow + 405;
            float wv[3][3];
            #pragma unroll
            for (int l = 0; l < 3; ++l)
                #pragma unroll
                for (int s = 0; s < 3; ++s)
                    wv[s][l] = Wa[(lt * 3 + l) * 3 + s];
            #pragma unroll
            for (int o = 0; o < 3; ++o) {
                float acc = 0.f;
                #pragma unroll
                for (int s = 0; s < 3; ++s)
                    #pragma unroll
                    for (int l = 0; l < 3; ++l)
                        acc += wv[s][l] * Ay[s * SS + o * SO + l * 3];
                V[lt * 3 + o] = acc;
            }
        }
        __syncthreads();
    }

    // ---- amplitude = Vf . Vb
    float partial = 0.f;
    for (int i = t; i < 729; i += 512) partial += Vsh[0][i] * Vsh[1][i];
    #pragma unroll
    for (int off = 32; off > 0; off >>= 1) partial += __shfl_down(partial, off);
    if ((t & 63) == 0) red[t >> 6] = partial;
    __syncthreads();
    if (t == 0) {
        float s = 0.f;
        #pragma unroll
        for (int w = 0; w < 8; ++w) s += red[w];
        out[b] = s;
    }
}

extern "C" void kernel_launch(void* const* d_in, const int* in_sizes, int n_in,
                              void* d_out, int out_size, void* d_ws, size_t ws_size,
                              hipStream_t stream) {
    const int* xs = (const int*)d_in[0];
    const float* T = (const float*)d_in[1];
    float* out = (float*)d_out;
    const int B = in_sizes[0] / 36;
    peps_amp_kernel<<<B, 512, 0, stream>>>(xs, T, out);
}

// Round 6
// 68.075 us; speedup vs baseline: 1.1885x; 1.0527x over previous
//
#include <hip/hip_runtime.h>

// PEPS 6x6 amplitude, D=3, B samples. Bidirectional boundary contraction
// (fwd waves 0-3: rows x=0..2; bwd waves 4-7: rows x=5..3), amp = Vf.Vb.
// Round-6: R3's light-phase structure + R5's verified fused2 y-pairs,
// plus (a) T cache-line prefetch overlapping the sidx computation
// (sidx only picks an element WITHIN a 128B line), (b) sidx via wave-0
// shuffles (no sg LDS phase), (c) wave-0-only final dot (no reduce syncs).
// 11 barriers total, all phases <=162 FMA/thread.
// A perm layout: u*27 + d*9 + l*3 + r. Fwd contracts u (SS=27), outputs
// d (SO=9); bwd contracts d (SS=9), outputs u (SO=27).

constexpr int SITE_STRIDE = 81 * 32; // floats per site in T

// Fused application of two y-sites. Input layout [D, l, s, m, ur(U)];
// output [(D,o1,o2,r2), ur(U)]. Verified in round 5.
template <int U>
__device__ __forceinline__ void fused2(int lt, const float* __restrict__ Win,
                                       float* __restrict__ Wout,
                                       const float* __restrict__ A1,
                                       const float* __restrict__ A2,
                                       int SS, int SO) {
    if (lt >= 243) return;
    const int D  = lt / (3 * U);
    const int rem = lt - D * 3 * U;
    const int o1 = rem / U;
    const int ur = rem - o1 * U;
    const float* Wb = Win + D * 27 * U + ur;
    float win[3][3][3]; // [l][s][m]
    #pragma unroll
    for (int l = 0; l < 3; ++l)
        #pragma unroll
        for (int s = 0; s < 3; ++s)
            #pragma unroll
            for (int m = 0; m < 3; ++m)
                win[l][s][m] = Wb[((l * 9 + s * 3 + m) * U)];
    float tt[3][3]; // [r1][m]
    #pragma unroll
    for (int r1 = 0; r1 < 3; ++r1)
        #pragma unroll
        for (int m = 0; m < 3; ++m) {
            float acc = 0.f;
            #pragma unroll
            for (int s = 0; s < 3; ++s)
                #pragma unroll
                for (int l = 0; l < 3; ++l)
                    acc += win[l][s][m] * A1[s * SS + o1 * SO + l * 3 + r1];
            tt[r1][m] = acc;
        }
    float* Wo = Wout + (D * 3 + o1) * 9 * U + ur;
    #pragma unroll
    for (int o2 = 0; o2 < 3; ++o2)
        #pragma unroll
        for (int r2 = 0; r2 < 3; ++r2) {
            float acc = 0.f;
            #pragma unroll
            for (int m = 0; m < 3; ++m)
                #pragma unroll
                for (int r1 = 0; r1 < 3; ++r1)
                    acc += tt[r1][m] * A2[m * SS + o2 * SO + r1 * 3 + r2];
            Wo[(o2 * 3 + r2) * U] = acc;
        }
}

__global__ __launch_bounds__(512)
void peps_amp_kernel(const int* __restrict__ xs, const float* __restrict__ T,
                     float* __restrict__ out) {
    __shared__ float A[36 * 81];
    __shared__ float Vsh[2][729];
    __shared__ float Wsh[2][2][2187];
    __shared__ int sidx[36];

    const int b = blockIdx.x;
    const int t = threadIdx.x;
    const int half = t >> 8;   // 0 = fwd (x=0,1,2), 1 = bwd (x=5,4,3)
    const int lt = t & 255;
    const int base = b * 36;

    // ---- issue T line prefetch (independent loads; sidx only selects
    // within each 128B line, so the line address needs no sidx)
    float pf = 0.f;
    #pragma unroll
    for (int ii = 0; ii < 6; ++ii) {
        const int idx = t + ii * 512;
        if (idx < 2916) {
            const int site = idx / 81;
            const int perm = idx - site * 81;
            pf += T[site * SITE_STRIDE + perm * 32];
        }
    }

    // ---- wave 0: sidx via shuffles (overlaps with prefetch in flight)
    if (t < 64) {
        const int xv = (t < 36) ? xs[base + t] : 0;
        const int lu = (t >= 6) ? t - 6 : 0;
        const int ll = (t >= 1) ? t - 1 : 0;
        const int ld = (t + 6 < 64) ? t + 6 : 0;
        const int lr = (t + 1 < 64) ? t + 1 : 0;
        const int vu = __shfl(xv, lu, 64);
        const int vd = __shfl(xv, ld, 64);
        const int vl = __shfl(xv, ll, 64);
        const int vr = __shfl(xv, lr, 64);
        if (t < 36) {
            const int i = t / 6, j = t - (t / 6) * 6;
            const int pu = (i > 0) ? vu : 0;
            const int pd = (i < 5) ? vd : 0;
            const int pl = (j > 0) ? vl : 0;
            const int pr = (j < 5) ? vr : 0;
            sidx[t] = (((xv * 2 + pu) * 2 + pd) * 2 + pl) * 2 + pr;
        }
    }
    __syncthreads();                                    // #1

    // ---- gather A slices (lines warm from prefetch)
    for (int idx = t; idx < 2916; idx += 512) {
        const int site = idx / 81;
        const int perm = idx - site * 81;
        A[idx] = T[site * SITE_STRIDE + perm * 32 + sidx[site]];
    }
    __syncthreads();                                    // #2

    const int SS = half ? 9 : 27;
    const int SO = half ? 27 : 9;
    float* V  = Vsh[half];
    float* Wa = Wsh[half][0];
    float* Wb = Wsh[half][1];

    // ---- boundary row chain (x=0 fwd / x=5 bwd), u resp. d pinned via SO
    {
        const float* Ab = &A[(half ? 30 : 0) * 81];
        for (int k = lt; k < 729; k += 256) {
            int c[6];
            c[0] = k / 243;
            c[1] = (k / 81) % 3;
            c[2] = (k / 27) % 3;
            c[3] = (k / 9) % 3;
            c[4] = (k / 3) % 3;
            c[5] = k % 3;
            float v0 = Ab[c[0] * SO + 0];
            float v1 = Ab[c[0] * SO + 1];
            float v2 = Ab[c[0] * SO + 2];
            #pragma unroll
            for (int y = 1; y <= 4; ++y) {
                const float* Ay = Ab + y * 81 + c[y] * SO;
                const float n0 = v0 * Ay[0] + v1 * Ay[3] + v2 * Ay[6];
                const float n1 = v0 * Ay[1] + v1 * Ay[4] + v2 * Ay[7];
                const float n2 = v0 * Ay[2] + v1 * Ay[5] + v2 * Ay[8];
                v0 = n0; v1 = n1; v2 = n2;
            }
            const float* A5 = Ab + 405 + c[5] * SO;
            V[k] = v0 * A5[0] + v1 * A5[3] + v2 * A5[6];
        }
    }
    __syncthreads();                                    // #3

    // ---- two interior rows per half, 4 phases each
    for (int cc = 0; cc < 2; ++cc) {
        const int xc = half ? (4 - cc) : (1 + cc);
        const float* Arow = &A[xc * 486];

        // y = 0 (l pinned 0): V[729] -> Wa[2187]
        if (lt < 243) {
            const float v0 = V[lt], v1 = V[243 + lt], v2 = V[486 + lt];
            const float* A0 = Arow;
            #pragma unroll
            for (int o = 0; o < 3; ++o)
                #pragma unroll
                for (int r = 0; r < 3; ++r) {
                    Wa[(o * 3 + r) * 243 + lt] =
                        v0 * A0[o * SO + r] +
                        v1 * A0[SS + o * SO + r] +
                        v2 * A0[2 * SS + o * SO + r];
                }
        }
        __syncthreads();                                // #4 / #8

        fused2<27>(lt, Wa, Wb, Arow + 81, Arow + 162, SS, SO);
        __syncthreads();                                // #5 / #9
        fused2<3>(lt, Wb, Wa, Arow + 243, Arow + 324, SS, SO);
        __syncthreads();                                // #6 / #10

        // y = 5 (r pinned 0): Wa[2187] -> V[729]
        if (lt < 243) {
            const float* Ay = Arow + 405;
            float wv[3][3];
            #pragma unroll
            for (int l = 0; l < 3; ++l)
                #pragma unroll
                for (int s = 0; s < 3; ++s)
                    wv[s][l] = Wa[(lt * 3 + l) * 3 + s];
            #pragma unroll
            for (int o = 0; o < 3; ++o) {
                float acc = 0.f;
                #pragma unroll
                for (int s = 0; s < 3; ++s)
                    #pragma unroll
                    for (int l = 0; l < 3; ++l)
                        acc += wv[s][l] * Ay[s * SS + o * SO + l * 3];
                V[lt * 3 + o] = acc;
            }
        }
        __syncthreads();                                // #7 / #11
    }

    // keep prefetch loads live (cheap: all vmem long since retired)
    asm volatile("" :: "v"(pf));

    // ---- amplitude = Vf . Vb, wave 0 only (no further barriers)
    if (t < 64) {
        float partial = 0.f;
        for (int i = t; i < 729; i += 64) partial += Vsh[0][i] * Vsh[1][i];
        #pragma unroll
        for (int off = 32; off > 0; off >>= 1) partial += __shfl_down(partial, off);
        if (t == 0) out[b] = partial;
    }
}

extern "C" void kernel_launch(void* const* d_in, const int* in_sizes, int n_in,
                              void* d_out, int out_size, void* d_ws, size_t ws_size,
                              hipStream_t stream) {
    const int* xs = (const int*)d_in[0];
    const float* T = (const float*)d_in[1];
    float* out = (float*)d_out;
    const int B = in_sizes[0] / 36;
    peps_amp_kernel<<<B, 512, 0, stream>>>(xs, T, out);
}